// Round 5
// baseline (197.011 us; speedup 1.0000x reference)
//
#include <hip/hip_runtime.h>

typedef __bf16 bf16;
typedef __bf16 bf16x8 __attribute__((ext_vector_type(8)));
typedef __bf16 bf16x4 __attribute__((ext_vector_type(4)));
typedef __bf16 bf16x2 __attribute__((ext_vector_type(2)));
typedef float  f32x4  __attribute__((ext_vector_type(4)));
typedef unsigned u32x2 __attribute__((ext_vector_type(2)));
typedef unsigned u32x4 __attribute__((ext_vector_type(4)));

#define DEV __device__ __forceinline__

// dtype probe: 1 if buffer looks like fp32, 0 if bf16.
// Lane-parallel: 1 load + ballot (R1: killed ~256 redundant scalar loads/thread).
DEV int detect_f32(const void* x) {
  const unsigned short* u = (const unsigned short*)x;
  int lane = threadIdx.x & 63;
  int e = (u[lane * 8] >> 7) & 0xFF;
  unsigned long long b = __ballot(e >= 118 && e <= 134);
  return __popcll(b) < 32;
}

DEV void gl2lds16(const bf16* g, bf16* l) {
  __builtin_amdgcn_global_load_lds(
      (const __attribute__((address_space(1))) void*)g,
      (__attribute__((address_space(3))) void*)l, 16, 0, 0);
}

// pack two f32 -> u32 of two bf16 (RNE); compiler fuses to v_cvt_pk_bf16_f32.
DEV unsigned pack_bf16(float a, float b) {
  bf16x2 t;
  t[0] = (bf16)a;
  t[1] = (bf16)b;
  return __builtin_bit_cast(unsigned, t);
}

// ---------------------------------------------------------------------------
// Kernel 1: prep = X+bias conversion to bf16 fused with weight transpose.
// Transpose LDS stride 80 (16B-aligned) so staging writes are ds_write_b128.
__global__ __launch_bounds__(256) void prep(
    const void* __restrict__ X, const void* __restrict__ bq,
    const void* __restrict__ bk, const void* __restrict__ bv,
    const void* __restrict__ bo, const void* __restrict__ Wq,
    const void* __restrict__ Wk, const void* __restrict__ Wv,
    const void* __restrict__ Wo, bf16* __restrict__ Xb,
    bf16* __restrict__ bqkv, bf16* __restrict__ bob,
    bf16* __restrict__ Wtqkv, bf16* __restrict__ Wto) {
  __shared__ __align__(16) bf16 T[64 * 80];
  int f32 = detect_f32(X);
  int blk = blockIdx.x, tid = threadIdx.x;
  if (blk < 2048) {
    long base = (long)blk * 2048 + tid * 8;
    bf16x8 o;
    if (f32) {
      const float* s = (const float*)X + base;
#pragma unroll
      for (int i = 0; i < 8; ++i) o[i] = (bf16)s[i];
    } else {
      o = *(const bf16x8*)((const bf16*)X + base);
    }
    *(bf16x8*)&Xb[base] = o;
  } else if (blk < 2052) {
    const void* src = (blk == 2048) ? bq : (blk == 2049) ? bk : (blk == 2050) ? bv : bo;
    bf16* dst = (blk == 2051) ? bob : bqkv + (blk - 2048) * 1024;
    int base = tid * 4;
    if (f32) {
      const float* s = (const float*)src;
#pragma unroll
      for (int i = 0; i < 4; ++i) dst[base + i] = (bf16)s[base + i];
    } else {
      const bf16* s = (const bf16*)src;
#pragma unroll
      for (int i = 0; i < 4; ++i) dst[base + i] = s[base + i];
    }
  } else {
    int id = blk - 2052;  // 0..1023
    int z = id >> 8, r = id & 255;
    int k0 = (r & 15) * 64, n0 = (r >> 4) * 64;
    const void* src = (z == 0) ? Wq : (z == 1) ? Wk : (z == 2) ? Wv : Wo;
    bf16* dst = (z < 3) ? (Wtqkv + (long)z * 1048576) : Wto;
#pragma unroll
    for (int c = 0; c < 2; ++c) {
      int lin = tid + c * 256;
      int row = lin >> 3, col8 = (lin & 7) * 8;
      long gidx = (long)(k0 + row) * 1024 + n0 + col8;
      bf16x8 v;
      if (f32) {
        const float* s = (const float*)src + gidx;
#pragma unroll
        for (int i = 0; i < 8; ++i) v[i] = (bf16)s[i];
      } else {
        v = *(const bf16x8*)((const bf16*)src + gidx);
      }
      *(bf16x8*)&T[row * 80 + col8] = v;
    }
    __syncthreads();
#pragma unroll
    for (int c = 0; c < 2; ++c) {
      int lin = tid + c * 256;
      int row = lin >> 3, col8 = (lin & 7) * 8;
      bf16x8 v;
#pragma unroll
      for (int i = 0; i < 8; ++i) v[i] = T[(col8 + i) * 80 + row];
      *(bf16x8*)&dst[(long)(n0 + row) * 1024 + k0 + col8] = v;
    }
  }
}

// ---------------------------------------------------------------------------
// Kernel 2: bf16 MFMA GEMM, C^T inner loop, TM x TN templated. XCD-aware
// bijective block swizzle (measured R4 A/B vs R2: ~-1.6us combined; keep —
// small positive, harmless). 128-wide tiles are the measured optimum for
// this 2-barrier structure (guide tile-space: 256² REGRESSES; dbuf null).
// MODE 0: C=A*Bt^T+bias -> Cout. MODE 1: QKV; Q/K packed [bh][s][dh]
// (Q pre-scaled by SCALE*log2e); V transposed THROUGH LDS then coalesced
// bf16x8 stores (scattered 8B stores at 4KB stride alias one L2 set -> 16x
// writeback amplification, measured R6).
template <int TM, int TN, int MODE>
__global__ __launch_bounds__(256, 3) void gemm_bt(
    const bf16* __restrict__ A, const bf16* __restrict__ Bt, int M, int N,
    int K, void* __restrict__ Cout, const bf16* __restrict__ bias,
    const void* __restrict__ detect_src, bf16* __restrict__ Qo,
    bf16* __restrict__ Ko, bf16* __restrict__ Vo) {
  constexpr int NWN = TN / 64;       // waves along n (1 or 2)
  constexpr int NWM = 4 / NWN;       // waves along m
  constexpr int MT = TM / (NWM * 16);
  __shared__ __align__(16) bf16 GS[TM * 64 + TN * 64];
  bf16* As = GS;
  bf16* Bs = GS + TM * 64;
  int tid = threadIdx.x, lane = tid & 63, wave = tid >> 6;
  int quad = lane >> 4, l16 = lane & 15;
  // XCD swizzle: grid sizes are multiples of 8 (768 / 512) -> bijective.
  int lin = blockIdx.x + blockIdx.y * gridDim.x;
  int cpx = (gridDim.x * gridDim.y) >> 3;
  int swz = (lin & 7) * cpx + (lin >> 3);
  int bx = swz % gridDim.x, by = swz / gridDim.x;
  int m0 = bx * TM, n0 = by * TN;
  int wm = (wave / NWN) * (TM / NWM), wn = (wave % NWN) * 64;
  f32x4 zero = {0.f, 0.f, 0.f, 0.f};
  f32x4 acc[MT][4];
#pragma unroll
  for (int i = 0; i < MT; ++i)
#pragma unroll
    for (int j = 0; j < 4; ++j) acc[i][j] = zero;

  for (int k0 = 0; k0 < K; k0 += 64) {
#pragma unroll
    for (int i = 0; i < TM / 32; ++i) {
      int u = (i * 4 + wave) * 64 + lane;
      int r = u >> 3, g = (u & 7) ^ (r & 7);
      gl2lds16(A + (long)(m0 + r) * K + k0 + g * 8, As + (i * 4 + wave) * 512);
    }
#pragma unroll
    for (int i = 0; i < TN / 32; ++i) {
      int u = (i * 4 + wave) * 64 + lane;
      int r = u >> 3, g = (u & 7) ^ (r & 7);
      gl2lds16(Bt + (long)(n0 + r) * K + k0 + g * 8, Bs + (i * 4 + wave) * 512);
    }
    __syncthreads();
#pragma unroll
    for (int kc = 0; kc < 2; ++kc) {
      bf16x8 bv_[4];
#pragma unroll
      for (int nt = 0; nt < 4; ++nt) {
        int row = wn + nt * 16 + l16;
        bv_[nt] = *(const bf16x8*)&Bs[row * 64 + (((kc * 4 + quad) ^ (l16 & 7))) * 8];
      }
#pragma unroll
      for (int mt = 0; mt < MT; ++mt) {
        int row = wm + mt * 16 + l16;
        bf16x8 af = *(const bf16x8*)&As[row * 64 + (((kc * 4 + quad) ^ (l16 & 7))) * 8];
#pragma unroll
        for (int nt = 0; nt < 4; ++nt)
          acc[mt][nt] = __builtin_amdgcn_mfma_f32_16x16x32_bf16(bv_[nt], af,
                                                                acc[mt][nt], 0, 0, 0);
      }
    }
    __syncthreads();
  }

  // epilogue: lane holds m = wm+mt*16+l16, n = wn+nt*16+quad*4+r (C^T)
  if (MODE == 0) {
    int f32o = detect_f32(detect_src);
#pragma unroll
    for (int nt = 0; nt < 4; ++nt) {
      int n = n0 + wn + nt * 16 + quad * 4;
      bf16x4 bb = *(const bf16x4*)&bias[n];
#pragma unroll
      for (int mt = 0; mt < MT; ++mt) {
        int m = m0 + wm + mt * 16 + l16;
        if (f32o) {
          f32x4 v;
#pragma unroll
          for (int r = 0; r < 4; ++r) v[r] = acc[mt][nt][r] + (float)bb[r];
          *(f32x4*)((float*)Cout + (long)m * N + n) = v;
        } else {
          bf16x4 v;
#pragma unroll
          for (int r = 0; r < 4; ++r) v[r] = (bf16)(acc[mt][nt][r] + (float)bb[r]);
          *(bf16x4*)((bf16*)Cout + (long)m * N + n) = v;
        }
      }
    }
  } else {
    int t = n0 >> 10;
    if (t < 2) {
      float qsc = (t == 0) ? 0.1803368801f : 1.0f;  // SCALE*log2(e) in Q
      bf16* op = (t == 0) ? Qo : Ko;
#pragma unroll
      for (int nt = 0; nt < 4; ++nt) {
        int n = n0 + wn + nt * 16 + quad * 4;
        bf16x4 bb = *(const bf16x4*)&bias[n];
        int nl = n & 1023, h = nl >> 6, dh = nl & 63;
#pragma unroll
        for (int mt = 0; mt < MT; ++mt) {
          int m = m0 + wm + mt * 16 + l16;
          int b = m >> 11, s = m & 2047;
          bf16x4 v;
#pragma unroll
          for (int r = 0; r < 4; ++r)
            v[r] = (bf16)((acc[mt][nt][r] + (float)bb[r]) * qsc);
          *(bf16x4*)&op[((long)(b * 16 + h) * 2048 + s) * 64 + dh] = v;
        }
      }
    } else {
      // V: bounce through LDS (As/Bs dead; GS = [128 n][128 m]), then
      // coalesced V^T stores. n = dh-dim (2 heads), m = s-dim.
      bf16* T = GS;
#pragma unroll
      for (int nt = 0; nt < 4; ++nt) {
        int n = wn + nt * 16 + quad * 4;
        bf16x4 bb = *(const bf16x4*)&bias[n0 + n];
#pragma unroll
        for (int mt = 0; mt < MT; ++mt) {
          int m = wm + mt * 16 + l16;
#pragma unroll
          for (int r = 0; r < 4; ++r)
            T[(n + r) * 128 + m] = (bf16)(acc[mt][nt][r] + (float)bb[r]);
        }
      }
      __syncthreads();
      int b = m0 >> 11, s0 = m0 & 2047;
      int h0 = (n0 & 1023) >> 6;
#pragma unroll
      for (int c = 0; c < 8; ++c) {
        int u = c * 256 + tid;
        int row = u >> 4, col = (u & 15) * 8;
        bf16x8 v = *(const bf16x8*)&T[row * 128 + col];
        long base =
            ((long)(b * 16 + h0 + (row >> 6)) * 64 + (row & 63)) * 2048 + s0;
        *(bf16x8*)&Vo[base + col] = v;
      }
    }
  }
}

// ---------------------------------------------------------------------------
// Kernel 3: attention, kv-split. R2-measured 42.4us loop structure kept
// VERBATIM in dependency terms (R3 lesson: the 4-deep mt-loop IS the
// software pipeline — do not shorten it). R5 deltas, both dependency-
// preserving: (a) exp2 results packed directly at final word positions in
// u32x4 pw[2][2] (static indices; kills the tt-reassembly movs; pb for half
// c still depends on exactly mt=2c,2c+1 — same dep graph as R2);
// (b) symmetric merge epilogue (correctness-proven inside R3's run): grp g
// exports nt=1-g / finalizes nt=g — half merge LDS traffic, stores on all
// 8 waves, post-loop only. 512 threads = 2 groups x 4 waves; group g eats
// kv tiles 2i+g; 4-buffer LDS ring, 1 barrier per tile-pair (vmcnt(0) at
// the barrier waits exactly for the pair needed next — depth-1 optimal).
// Staging offsets hoisted (R2). Register P; no-max softmax (Q pre-scaled
// by SCALE*log2e); lsum on the matrix pipe via ones-MFMA; XCD swizzle
// (R1: FETCH 70->12MB).
__global__ __launch_bounds__(512, 4) void attn(const bf16* __restrict__ Qg,
                                               const bf16* __restrict__ Kg,
                                               const bf16* __restrict__ Vtg,
                                               bf16* __restrict__ ctx) {
  __shared__ __align__(16) bf16 SMEM[32768];  // 64 KB
  bf16* Ksh = SMEM;          // 4 bufs x 4096
  bf16* Vsh = SMEM + 16384;  // 4 bufs x 4096
  float* MG = (float*)SMEM;  // merge region (aliases dead ring)

  int tid = threadIdx.x, lane = tid & 63, w = tid >> 6;
  int grp = w >> 2, wq = w & 3;
  int quad = lane >> 4, l16 = lane & 15;
  int lin = blockIdx.x | (blockIdx.y << 4);
  int swz = ((lin & 7) << 6) | (lin >> 3);
  int bh = swz >> 4, q0 = (swz & 15) << 7;
  const bf16* Qh = Qg + (long)bh * 131072;
  const bf16* Kh = Kg + (long)bh * 131072;
  const bf16* Vh = Vtg + (long)bh * 131072;
  int qbase = q0 + wq * 32;

  // Q fragments (read once from global)
  bf16x8 qf[2][2];
#pragma unroll
  for (int nt = 0; nt < 2; ++nt)
#pragma unroll
    for (int kc = 0; kc < 2; ++kc)
      qf[nt][kc] = *(const bf16x8*)&Qh[(long)(qbase + nt * 16 + l16) * 64 +
                                       kc * 32 + quad * 8];

  // fragment-read swizzle bases
  int e0 = l16 * 64 + (quad ^ (l16 & 7)) * 8;
  int e1 = l16 * 64 + ((4 + quad) ^ (l16 & 7)) * 8;

  // hoisted staging offsets (loop-invariant per thread)
  int mS = tid >> 3, gS = (tid & 7) ^ (mS & 7);
  int kvpS = (mS & 32) + ((mS & 12) << 1) + ((mS & 16) >> 2) + (mS & 3);
  int koff = kvpS * 64 + gS * 8;   // K: + tile*4096
  int voff = mS * 2048 + gS * 8;   // V: + tile*64
  int ldsoff = tid * 8;            // + buf*4096

  auto stage1 = [&](int t) {
    int buf = t & 3;
    gl2lds16(Kh + (long)t * 4096 + koff, Ksh + buf * 4096 + ldsoff);
    gl2lds16(Vh + t * 64 + voff, Vsh + buf * 4096 + ldsoff);
  };

  bf16x8 onesv;
#pragma unroll
  for (int i = 0; i < 8; ++i) onesv[i] = (bf16)1.0f;

  f32x4 zero = {0.f, 0.f, 0.f, 0.f};
  f32x4 O[2][4];
  f32x4 Ol[2] = {zero, zero};  // row-sum accumulator: Ol[nt] = ones * P^T
#pragma unroll
  for (int i = 0; i < 2; ++i)
#pragma unroll
    for (int j = 0; j < 4; ++j) O[i][j] = zero;

  auto compute = [&](const bf16* Kb, const bf16* Vb) {
    u32x4 pw[2][2];  // [c-half][nt] — exp2 packed at final word positions
#pragma unroll
    for (int mt = 0; mt < 4; ++mt) {
      bf16x8 kf0 = *(const bf16x8*)&Kb[e0 + mt * 1024];
      bf16x8 kf1 = *(const bf16x8*)&Kb[e1 + mt * 1024];
#pragma unroll
      for (int nt = 0; nt < 2; ++nt) {
        f32x4 s_ = zero;
        __builtin_amdgcn_s_setprio(1);
        s_ = __builtin_amdgcn_mfma_f32_16x16x32_bf16(kf0, qf[nt][0], s_, 0, 0, 0);
        s_ = __builtin_amdgcn_mfma_f32_16x16x32_bf16(kf1, qf[nt][1], s_, 0, 0, 0);
        __builtin_amdgcn_s_setprio(0);
        f32x4 p;
        p[0] = __builtin_amdgcn_exp2f(s_[0]);
        p[1] = __builtin_amdgcn_exp2f(s_[1]);
        p[2] = __builtin_amdgcn_exp2f(s_[2]);
        p[3] = __builtin_amdgcn_exp2f(s_[3]);
        pw[mt >> 1][nt][(mt & 1) * 2]     = pack_bf16(p[0], p[1]);
        pw[mt >> 1][nt][(mt & 1) * 2 + 1] = pack_bf16(p[2], p[3]);
      }
    }
#pragma unroll
    for (int c = 0; c < 2; ++c) {
      bf16x8 pb[2];
      pb[0] = __builtin_bit_cast(bf16x8, pw[c][0]);
      pb[1] = __builtin_bit_cast(bf16x8, pw[c][1]);
      int ec = c ? e1 : e0;
      __builtin_amdgcn_s_setprio(1);
#pragma unroll
      for (int dt = 0; dt < 4; ++dt) {
        bf16x8 vf = *(const bf16x8*)&Vb[ec + dt * 1024];
#pragma unroll
        for (int nt = 0; nt < 2; ++nt)
          O[nt][dt] = __builtin_amdgcn_mfma_f32_16x16x32_bf16(vf, pb[nt],
                                                              O[nt][dt], 0, 0, 0);
      }
      // lsum on the matrix pipe: D[i,q] = sum_k P[q,k] (identical in all rows)
#pragma unroll
      for (int nt = 0; nt < 2; ++nt)
        Ol[nt] = __builtin_amdgcn_mfma_f32_16x16x32_bf16(onesv, pb[nt],
                                                         Ol[nt], 0, 0, 0);
      __builtin_amdgcn_s_setprio(0);
    }
  };

  stage1(0);
  stage1(1);
  for (int it = 0; it < 16; ++it) {
    __syncthreads();      // pair {2it, 2it+1} visible
    int ta = 2 * it + 2;  // prefetch next pair (wave-uniform guard)
    if (ta < 32) {
      stage1(ta);
      stage1(ta + 1);
    }
    int t = 2 * it + grp;
    compute(Ksh + (t & 3) * 4096, Vsh + (t & 3) * 4096);
  }

  // every lane already holds the full kv-half row-sum (ones-MFMA), no shfl
  float lsum[2] = {Ol[0][0], Ol[1][0]};

  // symmetric merge: grp g EXPORTS nt=1-g to LDS, FINALIZES nt=g.
  __syncthreads();  // ring dead; safe to alias
  float* Mp = MG + wq * 2176;
  int nte = 1 - grp, ntf = grp;
#pragma unroll
  for (int dt = 0; dt < 4; ++dt)
    *(f32x4*)&Mp[((nte * 4 + dt) * 64 + lane) * 4] = O[nte][dt];
  Mp[2048 + nte * 64 + lane] = lsum[nte];
  __syncthreads();
#pragma unroll
  for (int dt = 0; dt < 4; ++dt) {
    f32x4 o2 = *(const f32x4*)&Mp[((ntf * 4 + dt) * 64 + lane) * 4];
#pragma unroll
    for (int r = 0; r < 4; ++r) O[ntf][dt][r] += o2[r];
  }
  float ls = lsum[ntf] + Mp[2048 + ntf * 64 + lane];
  float rv = __builtin_amdgcn_rcpf(ls);
  int b = bh >> 4, h = bh & 15;
  int s = qbase + ntf * 16 + l16;
#pragma unroll
  for (int dt = 0; dt < 4; ++dt) {
    bf16x4 v;
#pragma unroll
    for (int r = 0; r < 4; ++r) v[r] = (bf16)(O[ntf][dt][r] * rv);
    *(bf16x4*)&ctx[((long)(b * 2048 + s)) * 1024 + h * 64 + dt * 16 +
                   quad * 4] = v;
  }
}

// ---------------------------------------------------------------------------
extern "C" void kernel_launch(void* const* d_in, const int* in_sizes, int n_in,
                              void* d_out, int out_size, void* d_ws,
                              size_t ws_size, hipStream_t stream) {
  const void* X  = d_in[0];
  const void* Wq = d_in[1]; const void* bq = d_in[2];
  const void* Wk = d_in[3]; const void* bk = d_in[4];
  const void* Wv = d_in[5]; const void* bv = d_in[6];
  const void* Wo = d_in[7]; const void* bo = d_in[8];

  char* ws = (char*)d_ws;
  bf16* Xb    = (bf16*)(ws);               // 8,388,608 B
  bf16* Wtqkv = (bf16*)(ws + 8388608);     // 6,291,456 B
  bf16* Wto   = (bf16*)(ws + 14680064);    // 2,097,152 B
  bf16* bqkv  = (bf16*)(ws + 16777216);    // 6144 B
  bf16* bob   = (bf16*)(ws + 16783360);    // 2048 B
  bf16* Qw    = (bf16*)(ws + 16785408);    // [32][2048][64] pre-scaled
  bf16* Kw    = (bf16*)(ws + 25174016);    // [32][2048][64]
  bf16* Cx    = (bf16*)(ws + 33562624);    // [4096][1024]
  bf16* Vt    = (bf16*)(ws + 41951232);    // [32][64][2048] transposed

  prep<<<dim3(3076), 256, 0, stream>>>(X, bq, bk, bv, bo, Wq, Wk, Wv, Wo, Xb,
                                       bqkv, bob, Wtqkv, Wto);
  gemm_bt<128, 128, 1><<<dim3(32, 24), 256, 0, stream>>>(
      Xb, Wtqkv, 4096, 3072, 1024, nullptr, bqkv, nullptr, Qw, Kw, Vt);
  attn<<<dim3(16, 32), 512, 0, stream>>>(Qw, Kw, Vt, Cx);
  gemm_bt<128, 64, 0><<<dim3(32, 16), 256, 0, stream>>>(
      Cx, Wto, 4096, 1024, 1024, d_out, bob, X, nullptr, nullptr, nullptr);
}

// Round 6
// 176.405 us; speedup vs baseline: 1.1168x; 1.1168x over previous
//
#include <hip/hip_runtime.h>

typedef __bf16 bf16;
typedef __bf16 bf16x8 __attribute__((ext_vector_type(8)));
typedef __bf16 bf16x4 __attribute__((ext_vector_type(4)));
typedef __bf16 bf16x2 __attribute__((ext_vector_type(2)));
typedef float  f32x4  __attribute__((ext_vector_type(4)));
typedef unsigned u32x2 __attribute__((ext_vector_type(2)));
typedef unsigned u32x4 __attribute__((ext_vector_type(4)));

#define DEV __device__ __forceinline__

// dtype probe: 1 if buffer looks like fp32, 0 if bf16.
// Lane-parallel: 1 load + ballot (R1: killed ~256 redundant scalar loads/thread).
DEV int detect_f32(const void* x) {
  const unsigned short* u = (const unsigned short*)x;
  int lane = threadIdx.x & 63;
  int e = (u[lane * 8] >> 7) & 0xFF;
  unsigned long long b = __ballot(e >= 118 && e <= 134);
  return __popcll(b) < 32;
}

DEV void gl2lds16(const bf16* g, bf16* l) {
  __builtin_amdgcn_global_load_lds(
      (const __attribute__((address_space(1))) void*)g,
      (__attribute__((address_space(3))) void*)l, 16, 0, 0);
}

// pack two f32 -> u32 of two bf16 (RNE); compiler fuses to v_cvt_pk_bf16_f32.
DEV unsigned pack_bf16(float a, float b) {
  bf16x2 t;
  t[0] = (bf16)a;
  t[1] = (bf16)b;
  return __builtin_bit_cast(unsigned, t);
}

// ---------------------------------------------------------------------------
// Kernel 1: prep = X+bias conversion to bf16 fused with weight transpose.
// Transpose LDS stride 80 (16B-aligned) so staging writes are ds_write_b128.
__global__ __launch_bounds__(256) void prep(
    const void* __restrict__ X, const void* __restrict__ bq,
    const void* __restrict__ bk, const void* __restrict__ bv,
    const void* __restrict__ bo, const void* __restrict__ Wq,
    const void* __restrict__ Wk, const void* __restrict__ Wv,
    const void* __restrict__ Wo, bf16* __restrict__ Xb,
    bf16* __restrict__ bqkv, bf16* __restrict__ bob,
    bf16* __restrict__ Wtqkv, bf16* __restrict__ Wto) {
  __shared__ __align__(16) bf16 T[64 * 80];
  int f32 = detect_f32(X);
  int blk = blockIdx.x, tid = threadIdx.x;
  if (blk < 2048) {
    long base = (long)blk * 2048 + tid * 8;
    bf16x8 o;
    if (f32) {
      const float* s = (const float*)X + base;
#pragma unroll
      for (int i = 0; i < 8; ++i) o[i] = (bf16)s[i];
    } else {
      o = *(const bf16x8*)((const bf16*)X + base);
    }
    *(bf16x8*)&Xb[base] = o;
  } else if (blk < 2052) {
    const void* src = (blk == 2048) ? bq : (blk == 2049) ? bk : (blk == 2050) ? bv : bo;
    bf16* dst = (blk == 2051) ? bob : bqkv + (blk - 2048) * 1024;
    int base = tid * 4;
    if (f32) {
      const float* s = (const float*)src;
#pragma unroll
      for (int i = 0; i < 4; ++i) dst[base + i] = (bf16)s[base + i];
    } else {
      const bf16* s = (const bf16*)src;
#pragma unroll
      for (int i = 0; i < 4; ++i) dst[base + i] = s[base + i];
    }
  } else {
    int id = blk - 2052;  // 0..1023
    int z = id >> 8, r = id & 255;
    int k0 = (r & 15) * 64, n0 = (r >> 4) * 64;
    const void* src = (z == 0) ? Wq : (z == 1) ? Wk : (z == 2) ? Wv : Wo;
    bf16* dst = (z < 3) ? (Wtqkv + (long)z * 1048576) : Wto;
#pragma unroll
    for (int c = 0; c < 2; ++c) {
      int lin = tid + c * 256;
      int row = lin >> 3, col8 = (lin & 7) * 8;
      long gidx = (long)(k0 + row) * 1024 + n0 + col8;
      bf16x8 v;
      if (f32) {
        const float* s = (const float*)src + gidx;
#pragma unroll
        for (int i = 0; i < 8; ++i) v[i] = (bf16)s[i];
      } else {
        v = *(const bf16x8*)((const bf16*)src + gidx);
      }
      *(bf16x8*)&T[row * 80 + col8] = v;
    }
    __syncthreads();
#pragma unroll
    for (int c = 0; c < 2; ++c) {
      int lin = tid + c * 256;
      int row = lin >> 3, col8 = (lin & 7) * 8;
      bf16x8 v;
#pragma unroll
      for (int i = 0; i < 8; ++i) v[i] = T[(col8 + i) * 80 + row];
      *(bf16x8*)&dst[(long)(n0 + row) * 1024 + k0 + col8] = v;
    }
  }
}

// ---------------------------------------------------------------------------
// Kernel 2: bf16 MFMA GEMM, C^T inner loop, TM x TN templated. XCD-aware
// bijective block swizzle (measured R4 A/B vs R2: ~-1.6us combined; keep —
// small positive, harmless). 128-wide tiles are the measured optimum for
// this 2-barrier structure (guide tile-space: 256² REGRESSES; dbuf null).
// MODE 0: C=A*Bt^T+bias -> Cout. MODE 1: QKV; Q/K packed [bh][s][dh]
// (Q pre-scaled by SCALE*log2e); V transposed THROUGH LDS then coalesced
// bf16x8 stores (scattered 8B stores at 4KB stride alias one L2 set -> 16x
// writeback amplification, measured R6).
template <int TM, int TN, int MODE>
__global__ __launch_bounds__(256, 3) void gemm_bt(
    const bf16* __restrict__ A, const bf16* __restrict__ Bt, int M, int N,
    int K, void* __restrict__ Cout, const bf16* __restrict__ bias,
    const void* __restrict__ detect_src, bf16* __restrict__ Qo,
    bf16* __restrict__ Ko, bf16* __restrict__ Vo) {
  constexpr int NWN = TN / 64;       // waves along n (1 or 2)
  constexpr int NWM = 4 / NWN;       // waves along m
  constexpr int MT = TM / (NWM * 16);
  __shared__ __align__(16) bf16 GS[TM * 64 + TN * 64];
  bf16* As = GS;
  bf16* Bs = GS + TM * 64;
  int tid = threadIdx.x, lane = tid & 63, wave = tid >> 6;
  int quad = lane >> 4, l16 = lane & 15;
  // XCD swizzle: grid sizes are multiples of 8 (768 / 512) -> bijective.
  int lin = blockIdx.x + blockIdx.y * gridDim.x;
  int cpx = (gridDim.x * gridDim.y) >> 3;
  int swz = (lin & 7) * cpx + (lin >> 3);
  int bx = swz % gridDim.x, by = swz / gridDim.x;
  int m0 = bx * TM, n0 = by * TN;
  int wm = (wave / NWN) * (TM / NWM), wn = (wave % NWN) * 64;
  f32x4 zero = {0.f, 0.f, 0.f, 0.f};
  f32x4 acc[MT][4];
#pragma unroll
  for (int i = 0; i < MT; ++i)
#pragma unroll
    for (int j = 0; j < 4; ++j) acc[i][j] = zero;

  for (int k0 = 0; k0 < K; k0 += 64) {
#pragma unroll
    for (int i = 0; i < TM / 32; ++i) {
      int u = (i * 4 + wave) * 64 + lane;
      int r = u >> 3, g = (u & 7) ^ (r & 7);
      gl2lds16(A + (long)(m0 + r) * K + k0 + g * 8, As + (i * 4 + wave) * 512);
    }
#pragma unroll
    for (int i = 0; i < TN / 32; ++i) {
      int u = (i * 4 + wave) * 64 + lane;
      int r = u >> 3, g = (u & 7) ^ (r & 7);
      gl2lds16(Bt + (long)(n0 + r) * K + k0 + g * 8, Bs + (i * 4 + wave) * 512);
    }
    __syncthreads();
#pragma unroll
    for (int kc = 0; kc < 2; ++kc) {
      bf16x8 bv_[4];
#pragma unroll
      for (int nt = 0; nt < 4; ++nt) {
        int row = wn + nt * 16 + l16;
        bv_[nt] = *(const bf16x8*)&Bs[row * 64 + (((kc * 4 + quad) ^ (l16 & 7))) * 8];
      }
#pragma unroll
      for (int mt = 0; mt < MT; ++mt) {
        int row = wm + mt * 16 + l16;
        bf16x8 af = *(const bf16x8*)&As[row * 64 + (((kc * 4 + quad) ^ (l16 & 7))) * 8];
#pragma unroll
        for (int nt = 0; nt < 4; ++nt)
          acc[mt][nt] = __builtin_amdgcn_mfma_f32_16x16x32_bf16(bv_[nt], af,
                                                                acc[mt][nt], 0, 0, 0);
      }
    }
    __syncthreads();
  }

  // epilogue: lane holds m = wm+mt*16+l16, n = wn+nt*16+quad*4+r (C^T)
  if (MODE == 0) {
    int f32o = detect_f32(detect_src);
#pragma unroll
    for (int nt = 0; nt < 4; ++nt) {
      int n = n0 + wn + nt * 16 + quad * 4;
      bf16x4 bb = *(const bf16x4*)&bias[n];
#pragma unroll
      for (int mt = 0; mt < MT; ++mt) {
        int m = m0 + wm + mt * 16 + l16;
        if (f32o) {
          f32x4 v;
#pragma unroll
          for (int r = 0; r < 4; ++r) v[r] = acc[mt][nt][r] + (float)bb[r];
          *(f32x4*)((float*)Cout + (long)m * N + n) = v;
        } else {
          bf16x4 v;
#pragma unroll
          for (int r = 0; r < 4; ++r) v[r] = (bf16)(acc[mt][nt][r] + (float)bb[r]);
          *(bf16x4*)((bf16*)Cout + (long)m * N + n) = v;
        }
      }
    }
  } else {
    int t = n0 >> 10;
    if (t < 2) {
      float qsc = (t == 0) ? 0.1803368801f : 1.0f;  // SCALE*log2(e) in Q
      bf16* op = (t == 0) ? Qo : Ko;
#pragma unroll
      for (int nt = 0; nt < 4; ++nt) {
        int n = n0 + wn + nt * 16 + quad * 4;
        bf16x4 bb = *(const bf16x4*)&bias[n];
        int nl = n & 1023, h = nl >> 6, dh = nl & 63;
#pragma unroll
        for (int mt = 0; mt < MT; ++mt) {
          int m = m0 + wm + mt * 16 + l16;
          int b = m >> 11, s = m & 2047;
          bf16x4 v;
#pragma unroll
          for (int r = 0; r < 4; ++r)
            v[r] = (bf16)((acc[mt][nt][r] + (float)bb[r]) * qsc);
          *(bf16x4*)&op[((long)(b * 16 + h) * 2048 + s) * 64 + dh] = v;
        }
      }
    } else {
      // V: bounce through LDS (As/Bs dead; GS = [128 n][128 m]), then
      // coalesced V^T stores. n = dh-dim (2 heads), m = s-dim.
      bf16* T = GS;
#pragma unroll
      for (int nt = 0; nt < 4; ++nt) {
        int n = wn + nt * 16 + quad * 4;
        bf16x4 bb = *(const bf16x4*)&bias[n0 + n];
#pragma unroll
        for (int mt = 0; mt < MT; ++mt) {
          int m = wm + mt * 16 + l16;
#pragma unroll
          for (int r = 0; r < 4; ++r)
            T[(n + r) * 128 + m] = (bf16)(acc[mt][nt][r] + (float)bb[r]);
        }
      }
      __syncthreads();
      int b = m0 >> 11, s0 = m0 & 2047;
      int h0 = (n0 & 1023) >> 6;
#pragma unroll
      for (int c = 0; c < 8; ++c) {
        int u = c * 256 + tid;
        int row = u >> 4, col = (u & 15) * 8;
        bf16x8 v = *(const bf16x8*)&T[row * 128 + col];
        long base =
            ((long)(b * 16 + h0 + (row >> 6)) * 64 + (row & 63)) * 2048 + s0;
        *(bf16x8*)&Vo[base + col] = v;
      }
    }
  }
}

// ---------------------------------------------------------------------------
// Kernel 3: attention, kv-split — the R2/R4-measured 42.4us form, VERBATIM.
// DO NOT TOUCH the compute() body. Two measured lessons:
//   R3: shortening the 4-deep mt-loop (per-c-half interleave) starves the
//       matrix pipe on the serial exp2 chain (42->60us, MfmaUtil 36->25).
//   R5: packing exp2 results directly into u32x4 pw[c][nt] creates PARTIAL
//       WRITES into one 4-VGPR tuple -> write-after-write serialization of
//       the mt-chains; same collapse (42->54us). VGPR 60->52 is the red-flag
//       signature of both. Per-mt u32x2 pk[4][2] + late tt-reassembly IS the
//       correct form: separate tuples keep the 4 chains independent.
// 512 threads = 2 groups x 4 waves; wave = 32 q of a 128-q block of one
// (b,h). Group g eats kv tiles 2i+g. 4-buffer LDS ring, 1 barrier per
// tile-pair (depth-1 prefetch: vmcnt(0) at the barrier waits exactly for
// the pair needed next). Staging offsets hoisted (R2). Register P; no-max
// softmax (Q pre-scaled by SCALE*log2e); lsum on the matrix pipe via
// ones-MFMA; XCD swizzle (R1: FETCH 70->12MB).
__global__ __launch_bounds__(512, 4) void attn(const bf16* __restrict__ Qg,
                                               const bf16* __restrict__ Kg,
                                               const bf16* __restrict__ Vtg,
                                               bf16* __restrict__ ctx) {
  __shared__ __align__(16) bf16 SMEM[32768];  // 64 KB
  bf16* Ksh = SMEM;          // 4 bufs x 4096
  bf16* Vsh = SMEM + 16384;  // 4 bufs x 4096
  float* MG = (float*)SMEM;  // merge region (aliases dead ring)

  int tid = threadIdx.x, lane = tid & 63, w = tid >> 6;
  int grp = w >> 2, wq = w & 3;
  int quad = lane >> 4, l16 = lane & 15;
  int lin = blockIdx.x | (blockIdx.y << 4);
  int swz = ((lin & 7) << 6) | (lin >> 3);
  int bh = swz >> 4, q0 = (swz & 15) << 7;
  const bf16* Qh = Qg + (long)bh * 131072;
  const bf16* Kh = Kg + (long)bh * 131072;
  const bf16* Vh = Vtg + (long)bh * 131072;
  int qbase = q0 + wq * 32;

  // Q fragments (read once from global)
  bf16x8 qf[2][2];
#pragma unroll
  for (int nt = 0; nt < 2; ++nt)
#pragma unroll
    for (int kc = 0; kc < 2; ++kc)
      qf[nt][kc] = *(const bf16x8*)&Qh[(long)(qbase + nt * 16 + l16) * 64 +
                                       kc * 32 + quad * 8];

  // fragment-read swizzle bases
  int e0 = l16 * 64 + (quad ^ (l16 & 7)) * 8;
  int e1 = l16 * 64 + ((4 + quad) ^ (l16 & 7)) * 8;

  // hoisted staging offsets (loop-invariant per thread)
  int mS = tid >> 3, gS = (tid & 7) ^ (mS & 7);
  int kvpS = (mS & 32) + ((mS & 12) << 1) + ((mS & 16) >> 2) + (mS & 3);
  int koff = kvpS * 64 + gS * 8;   // K: + tile*4096
  int voff = mS * 2048 + gS * 8;   // V: + tile*64
  int ldsoff = tid * 8;            // + buf*4096

  auto stage1 = [&](int t) {
    int buf = t & 3;
    gl2lds16(Kh + (long)t * 4096 + koff, Ksh + buf * 4096 + ldsoff);
    gl2lds16(Vh + t * 64 + voff, Vsh + buf * 4096 + ldsoff);
  };

  bf16x8 onesv;
#pragma unroll
  for (int i = 0; i < 8; ++i) onesv[i] = (bf16)1.0f;

  f32x4 zero = {0.f, 0.f, 0.f, 0.f};
  f32x4 O[2][4];
  f32x4 Ol[2] = {zero, zero};  // row-sum accumulator: Ol[nt] = ones * P^T
#pragma unroll
  for (int i = 0; i < 2; ++i)
#pragma unroll
    for (int j = 0; j < 4; ++j) O[i][j] = zero;

  auto compute = [&](const bf16* Kb, const bf16* Vb) {
    u32x2 pk[4][2];
#pragma unroll
    for (int mt = 0; mt < 4; ++mt) {
      bf16x8 kf0 = *(const bf16x8*)&Kb[e0 + mt * 1024];
      bf16x8 kf1 = *(const bf16x8*)&Kb[e1 + mt * 1024];
#pragma unroll
      for (int nt = 0; nt < 2; ++nt) {
        f32x4 s_ = zero;
        __builtin_amdgcn_s_setprio(1);
        s_ = __builtin_amdgcn_mfma_f32_16x16x32_bf16(kf0, qf[nt][0], s_, 0, 0, 0);
        s_ = __builtin_amdgcn_mfma_f32_16x16x32_bf16(kf1, qf[nt][1], s_, 0, 0, 0);
        __builtin_amdgcn_s_setprio(0);
        f32x4 p;
        p[0] = __builtin_amdgcn_exp2f(s_[0]);
        p[1] = __builtin_amdgcn_exp2f(s_[1]);
        p[2] = __builtin_amdgcn_exp2f(s_[2]);
        p[3] = __builtin_amdgcn_exp2f(s_[3]);
        pk[mt][nt][0] = pack_bf16(p[0], p[1]);
        pk[mt][nt][1] = pack_bf16(p[2], p[3]);
      }
    }
#pragma unroll
    for (int c = 0; c < 2; ++c) {
      bf16x8 pb[2];
#pragma unroll
      for (int nt = 0; nt < 2; ++nt) {
        u32x4 tt;
        tt[0] = pk[2 * c][nt][0];
        tt[1] = pk[2 * c][nt][1];
        tt[2] = pk[2 * c + 1][nt][0];
        tt[3] = pk[2 * c + 1][nt][1];
        pb[nt] = __builtin_bit_cast(bf16x8, tt);
      }
      int ec = c ? e1 : e0;
      __builtin_amdgcn_s_setprio(1);
#pragma unroll
      for (int dt = 0; dt < 4; ++dt) {
        bf16x8 vf = *(const bf16x8*)&Vb[ec + dt * 1024];
#pragma unroll
        for (int nt = 0; nt < 2; ++nt)
          O[nt][dt] = __builtin_amdgcn_mfma_f32_16x16x32_bf16(vf, pb[nt],
                                                              O[nt][dt], 0, 0, 0);
      }
      // lsum on the matrix pipe: D[i,q] = sum_k P[q,k] (identical in all rows)
#pragma unroll
      for (int nt = 0; nt < 2; ++nt)
        Ol[nt] = __builtin_amdgcn_mfma_f32_16x16x32_bf16(onesv, pb[nt],
                                                         Ol[nt], 0, 0, 0);
      __builtin_amdgcn_s_setprio(0);
    }
  };

  stage1(0);
  stage1(1);
  for (int it = 0; it < 16; ++it) {
    __syncthreads();      // pair {2it, 2it+1} visible
    int ta = 2 * it + 2;  // prefetch next pair (wave-uniform guard)
    if (ta < 32) {
      stage1(ta);
      stage1(ta + 1);
    }
    int t = 2 * it + grp;
    compute(Ksh + (t & 3) * 4096, Vsh + (t & 3) * 4096);
  }

  // every lane already holds the full kv-half row-sum (ones-MFMA), no shfl
  float lsum[2] = {Ol[0][0], Ol[1][0]};

  // merge kv-halves: group1 -> LDS, group0 adds + normalizes + stores
  __syncthreads();  // ring dead; safe to alias
  float* Mp = MG + wq * 2176;
  if (grp == 1) {
#pragma unroll
    for (int nt = 0; nt < 2; ++nt) {
#pragma unroll
      for (int dt = 0; dt < 4; ++dt)
        *(f32x4*)&Mp[((nt * 4 + dt) * 64 + lane) * 4] = O[nt][dt];
      Mp[2048 + nt * 64 + lane] = lsum[nt];
    }
  }
  __syncthreads();
  if (grp == 0) {
#pragma unroll
    for (int nt = 0; nt < 2; ++nt) {
#pragma unroll
      for (int dt = 0; dt < 4; ++dt) {
        f32x4 o2 = *(const f32x4*)&Mp[((nt * 4 + dt) * 64 + lane) * 4];
#pragma unroll
        for (int r = 0; r < 4; ++r) O[nt][dt][r] += o2[r];
      }
      lsum[nt] += Mp[2048 + nt * 64 + lane];
    }
    float rv[2];
#pragma unroll
    for (int nt = 0; nt < 2; ++nt) rv[nt] = __builtin_amdgcn_rcpf(lsum[nt]);
    int b = bh >> 4, h = bh & 15;
#pragma unroll
    for (int nt = 0; nt < 2; ++nt) {
      int s = qbase + nt * 16 + l16;
#pragma unroll
      for (int dt = 0; dt < 4; ++dt) {
        bf16x4 v;
#pragma unroll
        for (int r = 0; r < 4; ++r) v[r] = (bf16)(O[nt][dt][r] * rv[nt]);
        *(bf16x4*)&ctx[((long)(b * 2048 + s)) * 1024 + h * 64 + dt * 16 +
                       quad * 4] = v;
      }
    }
  }
}

// ---------------------------------------------------------------------------
extern "C" void kernel_launch(void* const* d_in, const int* in_sizes, int n_in,
                              void* d_out, int out_size, void* d_ws,
                              size_t ws_size, hipStream_t stream) {
  const void* X  = d_in[0];
  const void* Wq = d_in[1]; const void* bq = d_in[2];
  const void* Wk = d_in[3]; const void* bk = d_in[4];
  const void* Wv = d_in[5]; const void* bv = d_in[6];
  const void* Wo = d_in[7]; const void* bo = d_in[8];

  char* ws = (char*)d_ws;
  bf16* Xb    = (bf16*)(ws);               // 8,388,608 B
  bf16* Wtqkv = (bf16*)(ws + 8388608);     // 6,291,456 B
  bf16* Wto   = (bf16*)(ws + 14680064);    // 2,097,152 B
  bf16* bqkv  = (bf16*)(ws + 16777216);    // 6144 B
  bf16* bob   = (bf16*)(ws + 16783360);    // 2048 B
  bf16* Qw    = (bf16*)(ws + 16785408);    // [32][2048][64] pre-scaled
  bf16* Kw    = (bf16*)(ws + 25174016);    // [32][2048][64]
  bf16* Cx    = (bf16*)(ws + 33562624);    // [4096][1024]
  bf16* Vt    = (bf16*)(ws + 41951232);    // [32][64][2048] transposed

  prep<<<dim3(3076), 256, 0, stream>>>(X, bq, bk, bv, bo, Wq, Wk, Wv, Wo, Xb,
                                       bqkv, bob, Wtqkv, Wto);
  gemm_bt<128, 128, 1><<<dim3(32, 24), 256, 0, stream>>>(
      Xb, Wtqkv, 4096, 3072, 1024, nullptr, bqkv, nullptr, Qw, Kw, Vt);
  attn<<<dim3(16, 32), 512, 0, stream>>>(Qw, Kw, Vt, Cx);
  gemm_bt<128, 64, 0><<<dim3(32, 16), 256, 0, stream>>>(
      Cx, Wto, 4096, 1024, 1024, d_out, bob, X, nullptr, nullptr, nullptr);
}